// Round 5
// baseline (355.833 us; speedup 1.0000x reference)
//
#include <hip/hip_runtime.h>

typedef float  f32x4 __attribute__((ext_vector_type(4)));
typedef short  s16x8 __attribute__((ext_vector_type(8)));

#define EPS_LN2      0.0017328679513998632f   /* eps*ln2, eps = 0.0025 */
#define INV_EPS_LN2  577.0780163555852f       /* 1/(eps*ln2) */
#define LOG2_36      5.169925001442312f

__device__ __forceinline__ short f2bf(float x) {
  unsigned int u; __builtin_memcpy(&u, &x, 4);
  u = (u + 0x7FFFu + ((u >> 16) & 1u)) >> 16;   // RNE
  return (short)u;
}

// ---------------------------------------------------------------------------
// k_prep: blocks [0,88) pack W_rt/W_ri into MFMA B-frag order (bf16);
// blocks [88,456) K-split GEMM writing per-job slices pre[23][128][200].
// ---------------------------------------------------------------------------
__global__ __launch_bounds__(256) void k_prep(
    const float* __restrict__ W_rt, const float* __restrict__ W_ri,
    short* __restrict__ frt, short* __restrict__ fri,
    const float* __restrict__ txt, const float* __restrict__ img,
    const float* __restrict__ social,
    const float* __restrict__ W_stat, const float* __restrict__ b_stat,
    const float* __restrict__ W_gt, const float* __restrict__ W_gi,
    float* __restrict__ pre) {
  __shared__ float sA[32][128];
  int bid = blockIdx.x;
  if (bid < 88) {
    // ---- pack ----
    int slot = bid * 256 + threadIdx.x;   // 22528 total
    const float* W; short* dst; int f;
    if (slot < 6144) { W = W_rt; dst = frt; f = slot; }
    else             { W = W_ri; dst = fri; f = slot - 6144; }
    int k32 = f >> 8, rem = f & 255, ct = rem >> 6, l = rem & 63;
    int col = ct * 16 + (l & 15);
    int k0  = k32 * 32 + (l >> 4) * 8;
    s16x8 p;
#pragma unroll
    for (int c = 0; c < 8; ++c) {
      float v = (col < 50) ? W[(k0 + c) * 50 + col] : 0.f;
      p[c] = f2bf(v);
    }
    *(s16x8*)(dst + (long)f * 8) = p;
    return;
  }
  // ---- gemm: job slice pre[job] = A_chunk @ W_chunk ----
  int gb = bid - 88;
  int job = gb >> 4, rb = (gb >> 2) & 3, cb = gb & 3;
  int t = threadIdx.x, r0 = rb * 32;
  const float* W; int k0, klen;
  if (job < 6)       { k0 = job * 128;       klen = 128; W = W_gt; }
  else if (job == 6) { k0 = 0;               klen = 100; W = W_gt + 768 * 200; }
  else               { k0 = (job - 7) * 128; klen = 128; W = W_gi; }
  if (job == 6) {
    for (int idx = t; idx < 4096; idx += 256) {
      int r = idx >> 7, k = idx & 127;
      float v = 0.f;
      if (k < 100) {
        v = b_stat[k];
#pragma unroll
        for (int u = 0; u < 10; ++u) v += social[(r0 + r) * 10 + u] * W_stat[u * 100 + k];
        v = fmaxf(v, 0.f);
      }
      sA[r][k] = v;
    }
  } else {
    const float* A = (job < 6) ? txt : img;
    int K_A = (job < 6) ? 768 : 2048;
    for (int idx = t; idx < 4096; idx += 256) {
      int r = idx >> 7, k = idx & 127;
      sA[r][k] = A[(r0 + r) * K_A + k0 + k];
    }
  }
  __syncthreads();
  int c = cb * 64 + (t & 63), rg = t >> 6;
  if (c < 200) {
    float acc[8];
#pragma unroll
    for (int i = 0; i < 8; ++i) acc[i] = 0.f;
    for (int k4 = 0; k4 < klen; k4 += 4) {
      float w0 = W[(k0 + k4    ) * 200 + c];
      float w1 = W[(k0 + k4 + 1) * 200 + c];
      float w2 = W[(k0 + k4 + 2) * 200 + c];
      float w3 = W[(k0 + k4 + 3) * 200 + c];
#pragma unroll
      for (int i = 0; i < 8; ++i) {
        f32x4 a = *(const f32x4*)&sA[rg * 8 + i][k4];
        acc[i] += a[0]*w0 + a[1]*w1 + a[2]*w2 + a[3]*w3;
      }
    }
    float* dst = pre + (long)job * 25600;
#pragma unroll
    for (int i = 0; i < 8; ++i)
      dst[(r0 + rg * 8 + i) * 200 + c] = acc[i];
  }
}

// ---------------------------------------------------------------------------
// Projection GEMM body, register-double-buffered A stream (no LDS):
// chunks of 4 k32 (128 cols); while consuming chunk c, chunk c+1's eight
// independent dwordx4 loads are in flight (8 KB/wave). B-frags from L2.
// out[M][64] = relu(A[M][K] @ W + bias). One block = 64 rows (4 waves x 16).
// ---------------------------------------------------------------------------
template<int K32>
__device__ __forceinline__ void proj_body(const float* __restrict__ A,
                                          const short* __restrict__ Bf,
                                          const float* __restrict__ bias,
                                          float* __restrict__ out, int bid) {
  constexpr int NC = K32 / 4;
  int wave = threadIdx.x >> 6, lane = threadIdx.x & 63;
  int rl = lane & 15, q = lane >> 4;
  int row0 = bid * 64 + wave * 16;
  const int K = K32 * 32;
  const float* ar = A + (long)(row0 + rl) * K + q * 8;
  const short* bfl = Bf + lane * 8;

  f32x4 buf[2][8];
#pragma unroll
  for (int u = 0; u < 8; ++u)
    buf[0][u] = *(const f32x4*)(ar + (u >> 1) * 32 + (u & 1) * 4);
#pragma unroll
  for (int u = 0; u < 8; ++u)
    buf[1][u] = *(const f32x4*)(ar + 128 + (u >> 1) * 32 + (u & 1) * 4);

  f32x4 acc[4];
#pragma unroll
  for (int ct = 0; ct < 4; ++ct) acc[ct] = (f32x4){0.f, 0.f, 0.f, 0.f};

  for (int c = 0; c < NC; ++c) {
    f32x4* cur = buf[c & 1];
#pragma unroll
    for (int kk = 0; kk < 4; ++kk) {
      int k32 = c * 4 + kk;
      f32x4 a0 = cur[kk * 2], a1 = cur[kk * 2 + 1];
      s16x8 af;
      af[0]=f2bf(a0[0]); af[1]=f2bf(a0[1]); af[2]=f2bf(a0[2]); af[3]=f2bf(a0[3]);
      af[4]=f2bf(a1[0]); af[5]=f2bf(a1[1]); af[6]=f2bf(a1[2]); af[7]=f2bf(a1[3]);
      const short* bp = bfl + (long)k32 * 2048;
#pragma unroll
      for (int ct = 0; ct < 4; ++ct) {
        s16x8 bfr = *(const s16x8*)(bp + ct * 512);
        acc[ct] = __builtin_amdgcn_mfma_f32_16x16x32_bf16(af, bfr, acc[ct], 0, 0, 0);
      }
    }
    if (c + 2 < NC) {
      const float* src = ar + (c + 2) * 128;
#pragma unroll
      for (int u = 0; u < 8; ++u)
        cur[u] = *(const f32x4*)(src + (u >> 1) * 32 + (u & 1) * 4);
    }
  }
#pragma unroll
  for (int ct = 0; ct < 4; ++ct) {
    int col = ct * 16 + rl;
    float bv = (col < 50) ? bias[col] : 0.f;
#pragma unroll
    for (int r = 0; r < 4; ++r) {
      int grow = row0 + q * 4 + r;               // D row = quad*4+reg (m89)
      float o = fmaxf(acc[ct][r] + bv, 0.f);
      out[(long)grow * 64 + col] = (col < 50) ? o : 0.f;
    }
  }
}

// MLP tail body: one block per batch row; sums the 23 per-job GEMM slices.
__device__ __forceinline__ void mix_body(
    int r, const float* __restrict__ pre,
    const float* __restrict__ b_gt, const float* __restrict__ b_gi,
    const float* __restrict__ W_m1, const float* __restrict__ b_m1,
    const float* __restrict__ W_m2, const float* __restrict__ b_m2,
    float* __restrict__ mix, char* smem) {
  float* sm = (float*)smem;          // [200]
  float* sh = (float*)(smem + 800);  // [100]
  int t = threadIdx.x;
  if (t < 200) {
    float s1 = b_gt[t], s2 = b_gi[t];
#pragma unroll
    for (int j = 0; j < 7; ++j)  s1 += pre[(long)j * 25600 + r * 200 + t];
#pragma unroll
    for (int j = 7; j < 23; ++j) s2 += pre[(long)j * 25600 + r * 200 + t];
    sm[t] = fmaxf(s1, 0.f) + fmaxf(s2, 0.f);
  }
  __syncthreads();
  if (t < 100) {
    float a = b_m1[t];
#pragma unroll 4
    for (int k = 0; k < 200; ++k) a += sm[k] * W_m1[k * 100 + t];
    sh[t] = fmaxf(a, 0.f);
  }
  __syncthreads();
  if (t < 2) {
    float a = b_m2[t];
    for (int k = 0; k < 100; ++k) a += sh[k] * W_m2[k * 2 + t];
    mix[r * 2 + t] = a;
  }
}

// Merged: blocks [0,128) mix rows, [128,640) txt proj, [640,712) img proj.
__global__ __launch_bounds__(256)
__attribute__((amdgpu_waves_per_eu(4, 4)))
void k_pm(
    const float* __restrict__ txt_region, const short* __restrict__ frt,
    const float* __restrict__ b_rt, float* __restrict__ tr,
    const float* __restrict__ img_region, const short* __restrict__ fri,
    const float* __restrict__ b_ri, float* __restrict__ ir,
    const float* __restrict__ pre,
    const float* __restrict__ b_gt, const float* __restrict__ b_gi,
    const float* __restrict__ W_m1, const float* __restrict__ b_m1,
    const float* __restrict__ W_m2, const float* __restrict__ b_m2,
    float* __restrict__ mix) {
  __shared__ __align__(16) char smem[2048];
  int bid = blockIdx.x;
  if (bid < 128)      mix_body(bid, pre, b_gt, b_gi, W_m1, b_m1, W_m2, b_m2, mix, smem);
  else if (bid < 640) proj_body<24>(txt_region, frt, b_rt, tr, bid - 128);
  else                proj_body<64>(img_region, fri, b_ri, ir, bid - 640);
}

// ---------------------------------------------------------------------------
// Merged Sinkhorn kernel, MAX-PLUS. role 0: xx (n x n), role 1: xy (n x 36),
// role 2: yy (36 x 36). waves_per_eu(4,4): 128-VGPR budget, Creg in regs.
// ---------------------------------------------------------------------------
#define SK_SMEM 50736

__global__ __launch_bounds__(1024)
__attribute__((amdgpu_waves_per_eu(4, 4)))
void k_sink(
    const float* __restrict__ tr, const float* __restrict__ ir,
    const int* __restrict__ amask, float* __restrict__ Cxx,
    float* __restrict__ Sxy, float* __restrict__ Sxx, float* __restrict__ Syy) {
  __shared__ __align__(16) char smem[SK_SMEM];
  int role = blockIdx.x >> 7;
  int b    = blockIdx.x & 127;
  int tid  = threadIdx.x;

  if (role == 0) {
    // ====================== XX ======================
    short* Xf    = (short*)smem;                 // 32 KB
    float* norms = (float*)(smem + 32768);       // [256]
    float* sA    = (float*)(smem + 33792);       // [256]
    float* sF    = (float*)(smem + 34816);       // [256]
    float* sG    = (float*)(smem + 35840);       // [256]
    float* sPm   = (float*)(smem + 36864);       // [4][256]
    int*   nsh   = (int*)  (smem + 40960);
    if (tid < 64) {
      int c = 0;
      for (int i = tid; i < 256; i += 64) c += amask[b * 256 + i];
#pragma unroll
      for (int o = 1; o < 64; o <<= 1) c += __shfl_xor(c, o);
      if (tid == 0) *nsh = c;
    }
    const float* Xg = tr + (long)b * 256 * 64;
    for (int slot = tid; slot < 2048; slot += 1024) {
      int t = slot >> 7, k32 = (slot >> 6) & 1, l = slot & 63;
      int row = t * 16 + (l & 15), k0 = k32 * 32 + (l >> 4) * 8;
      const float* src = Xg + row * 64 + k0;
      f32x4 a0 = *(const f32x4*)src, a1 = *(const f32x4*)(src + 4);
      s16x8 p;
      p[0]=f2bf(a0[0]); p[1]=f2bf(a0[1]); p[2]=f2bf(a0[2]); p[3]=f2bf(a0[3]);
      p[4]=f2bf(a1[0]); p[5]=f2bf(a1[1]); p[6]=f2bf(a1[2]); p[7]=f2bf(a1[3]);
      *(s16x8*)(Xf + slot * 8) = p;
    }
    __syncthreads();
    int n = *nsh;
    // G = X X^T via MFMA. wave wv owns 16-row strip.
    int wv = tid >> 6, lane = tid & 63, q = lane >> 4;
    f32x4 acc[16];
#pragma unroll
    for (int ct = 0; ct < 16; ++ct) acc[ct] = (f32x4){0.f, 0.f, 0.f, 0.f};
    s16x8 afr0 = *(const s16x8*)(Xf + ((wv * 2 + 0) * 64 + lane) * 8);
    s16x8 afr1 = *(const s16x8*)(Xf + ((wv * 2 + 1) * 64 + lane) * 8);
#pragma unroll
    for (int ct = 0; ct < 16; ++ct) {
      s16x8 b0 = *(const s16x8*)(Xf + ((ct * 2 + 0) * 64 + lane) * 8);
      s16x8 b1 = *(const s16x8*)(Xf + ((ct * 2 + 1) * 64 + lane) * 8);
      acc[ct] = __builtin_amdgcn_mfma_f32_16x16x32_bf16(afr0, b0, acc[ct], 0, 0, 0);
      acc[ct] = __builtin_amdgcn_mfma_f32_16x16x32_bf16(afr1, b1, acc[ct], 0, 0, 0);
    }
#pragma unroll
    for (int r = 0; r < 4; ++r) {                 // diag of tile (wv,wv) = ||x||^2
      int m_ = q * 4 + r;
      if ((lane & 15) == m_) norms[wv * 16 + m_] = acc[wv][r];
    }
    __syncthreads();
    float* Cwb = Cxx + (long)b * 65536;           // D = -C/(eps ln2), f32, global
    if (wv * 16 < n) {                            // skip row-tiles entirely >= n
#pragma unroll
      for (int ct = 0; ct < 16; ++ct) {
        int gj = ct * 16 + (lane & 15);
        float nj = norms[gj];
#pragma unroll
        for (int r = 0; r < 4; ++r) {
          int gi = wv * 16 + q * 4 + r;
          Cwb[gi * 256 + gj] = (acc[ct][r] - 0.5f * (norms[gi] + nj)) * INV_EPS_LN2;
        }
      }
    }
    __syncthreads();
    // kk wave-uniform so prefix-skipping has no divergence
    int kk = tid >> 8, j = tid & 255, i0 = kk * 64;
    int iend = n - i0; if (iend > 64) iend = 64;
    float Creg[64];
    if (j < n) {
#pragma unroll
      for (int ch = 0; ch < 4; ++ch) {
        if (ch * 16 < iend) {
#pragma unroll
          for (int u = 0; u < 16; ++u)
            Creg[ch * 16 + u] = Cwb[(i0 + ch * 16 + u) * 256 + j];
        }
      }
    }
    float log2n = log2f((float)n);
    if (tid < 256) { sF[tid] = 0.f; sA[tid] = (tid < n) ? -log2n : -1e30f; }
    __syncthreads();
    const float* ap = sA + i0;
    for (int h = 0; h < 40; ++h) {
      float m = -1e30f;
      if (j < n) {
#pragma unroll
        for (int ch = 0; ch < 4; ++ch) {
          if (ch * 16 < iend) {                   // wave-uniform chunk skip
            const float* app = ap + ch * 16;
            f32x4 A0 = *(const f32x4*)(app);
            f32x4 A1 = *(const f32x4*)(app + 4);
            f32x4 A2 = *(const f32x4*)(app + 8);
            f32x4 A3 = *(const f32x4*)(app + 12);
            float x0 = A0[0]+Creg[ch*16+0],  x1 = A0[1]+Creg[ch*16+1];
            float x2 = A0[2]+Creg[ch*16+2],  x3 = A0[3]+Creg[ch*16+3];
            float x4 = A1[0]+Creg[ch*16+4],  x5 = A1[1]+Creg[ch*16+5];
            float x6 = A1[2]+Creg[ch*16+6],  x7 = A1[3]+Creg[ch*16+7];
            float x8 = A2[0]+Creg[ch*16+8],  x9 = A2[1]+Creg[ch*16+9];
            float xa = A2[2]+Creg[ch*16+10], xb = A2[3]+Creg[ch*16+11];
            float xc = A3[0]+Creg[ch*16+12], xd = A3[1]+Creg[ch*16+13];
            float xe = A3[2]+Creg[ch*16+14], xf = A3[3]+Creg[ch*16+15];
            // max3 trees (v_max3_f32)
            float y0 = fmaxf(fmaxf(x0, x1), x2);
            float y1 = fmaxf(fmaxf(x3, x4), x5);
            float y2 = fmaxf(fmaxf(x6, x7), x8);
            float y3 = fmaxf(fmaxf(x9, xa), xb);
            float y4 = fmaxf(fmaxf(xc, xd), xe);
            float z0 = fmaxf(fmaxf(y0, y1), y2);
            float z1 = fmaxf(fmaxf(y3, y4), xf);
            m = fmaxf(fmaxf(m, z0), z1);
          }
        }
      }
      sPm[kk * 256 + j] = m;
      __syncthreads();
      if (tid < 256) {
        float m4 = fmaxf(fmaxf(sPm[tid], sPm[256 + tid]),
                         fmaxf(sPm[512 + tid], sPm[768 + tid]));
        if (tid < n) {
          ((h & 1) ? sF : sG)[tid] = -EPS_LN2 * m4;
          sA[tid] = -log2n - m4;
        }
      }
      __syncthreads();
    }
    if (tid < 64) {
      float a = 0.f;
      for (int i = tid; i < n; i += 64) a += sF[i] + sG[i];
#pragma unroll
      for (int o = 1; o < 64; o <<= 1) a += __shfl_xor(a, o);
      if (tid == 0) Sxx[b] = a / n;
    }
  } else if (role == 1) {
    // ====================== XY ======================
    float* Ys  = (float*)smem;                    // [36][64]
    float* Cs  = (float*)(smem + 9216);           // [256][37]
    float* nx  = (float*)(smem + 47104);          // [256]
    float* ny  = (float*)(smem + 48128);          // [36]
    float* sA  = (float*)(smem + 48288);          // padded alpha [272]
    float* sB  = (float*)(smem + 49376);          // beta [36]
    float* sF  = (float*)(smem + 49536);          // [256]
    float* sG  = (float*)(smem + 50560);          // [36]
    int*   nsh = (int*)  (smem + 50720);
    if (tid < 64) {
      int c = 0;
      for (int i = tid; i < 256; i += 64) c += amask[b * 256 + i];
#pragma unroll
      for (int o = 1; o < 64; o <<= 1) c += __shfl_xor(c, o);
      if (tid == 0) *nsh = c;
    }
    const float* Xg = tr + (long)b * 256 * 64;
    const float* Yg = ir + (long)b * 36 * 64;
    for (int idx = tid; idx < 576; idx += 1024) {
      int row = idx >> 4, q4 = idx & 15;
      *(f32x4*)(Ys + row * 64 + q4 * 4) = *(const f32x4*)(Yg + row * 64 + q4 * 4);
    }
    __syncthreads();
    int n = *nsh;
    if (tid < 256) {
      float a = 0.f;
#pragma unroll
      for (int q4 = 0; q4 < 13; ++q4) {
        f32x4 v = *(const f32x4*)(Xg + tid * 64 + q4 * 4);
        a += v[0]*v[0] + v[1]*v[1] + v[2]*v[2] + v[3]*v[3];
      }
      nx[tid] = a;
    } else if (tid < 292) {
      int jj = tid - 256; float a = 0.f;
#pragma unroll
      for (int q4 = 0; q4 < 13; ++q4) {
        f32x4 v = *(const f32x4*)(Ys + jj * 64 + q4 * 4);
        a += v[0]*v[0] + v[1]*v[1] + v[2]*v[2] + v[3]*v[3];
      }
      ny[jj] = a;
    }
    __syncthreads();
    if (tid < 1008) {
      int ii = tid / 36, jj = tid - ii * 36;
      f32x4 yr[13];
#pragma unroll
      for (int q4 = 0; q4 < 13; ++q4) yr[q4] = *(const f32x4*)(Ys + jj * 64 + q4 * 4);
      float nyj = ny[jj];
      for (int i = ii; i < 256; i += 28) {
        float d = 0.f;
#pragma unroll
        for (int q4 = 0; q4 < 13; ++q4) {
          f32x4 xv = *(const f32x4*)(Xg + i * 64 + q4 * 4);
          d += xv[0]*yr[q4][0] + xv[1]*yr[q4][1] + xv[2]*yr[q4][2] + xv[3]*yr[q4][3];
        }
        Cs[i * 37 + jj] = (d - 0.5f * (nx[i] + nyj)) * INV_EPS_LN2;
      }
    }
    __syncthreads();
    int jg = tid >> 4, kg = tid & 15;             // g-role: column jg, slice kg
    float Cg[16];
    if (jg < 36) {
#pragma unroll
      for (int t = 0; t < 16; ++t) Cg[t] = Cs[(kg * 16 + t) * 37 + jg];
    }
    int fi = tid >> 2, kf = tid & 3;              // f-role: row fi, slice kf
    float Cf[9];
#pragma unroll
    for (int t = 0; t < 9; ++t) {
      int jj2 = kf * 9 + t;
      Cf[t] = (jj2 < 36) ? Cs[fi * 37 + jj2] : 0.f;
    }
    float log2n = log2f((float)n);
    if (tid < 256) { sF[tid] = 0.f; sA[tid + (tid >> 4)] = -log2n; }
    __syncthreads();
    const float* agp = sA + kg * 17;
    int gend = n - kg * 16; if (gend > 16) gend = 16;
    for (int it = 0; it < 20; ++it) {
      float gm = -1e30f;
      if (jg < 36) {
#pragma unroll
        for (int t = 0; t < 16; ++t)
          if (t < gend) gm = fmaxf(gm, agp[t] + Cg[t]);
        gm = fmaxf(gm, __shfl_xor(gm, 1)); gm = fmaxf(gm, __shfl_xor(gm, 2));
        gm = fmaxf(gm, __shfl_xor(gm, 4)); gm = fmaxf(gm, __shfl_xor(gm, 8));
      }
      __syncthreads();
      if (jg < 36 && kg == 0) {
        sG[jg] = -EPS_LN2 * gm;
        sB[jg] = -LOG2_36 - gm;
      }
      __syncthreads();
      float fm = -1e30f;
#pragma unroll
      for (int t = 0; t < 9; ++t) {
        int jj2 = kf * 9 + t;
        if (jj2 < 36) fm = fmaxf(fm, sB[jj2] + Cf[t]);
      }
      fm = fmaxf(fm, __shfl_xor(fm, 1)); fm = fmaxf(fm, __shfl_xor(fm, 2));
      __syncthreads();
      if (kf == 0 && fi < n) {
        sF[fi] = -EPS_LN2 * fm;
        sA[fi + (fi >> 4)] = -log2n - fm;
      }
      __syncthreads();
    }
    if (tid < 64) {
      float a = 0.f;
      for (int i = tid; i < n; i += 64) a += sF[i];
      float g = (tid < 36) ? sG[tid] : 0.f;
#pragma unroll
      for (int o = 1; o < 64; o <<= 1) { a += __shfl_xor(a, o); g += __shfl_xor(g, o); }
      if (tid == 0) Sxy[b] = a / n + g / 36.f;
    }
  } else {
    // ====================== YY ======================
    float* Ys = (float*)smem;                     // [36][64]
    float* Cs = (float*)(smem + 9216);            // [36][37]
    float* ny = (float*)(smem + 48128);
    float* sA = (float*)(smem + 48288);           // [36]
    float* sF = (float*)(smem + 49536);
    float* sG = (float*)(smem + 50560);
    const float* Yg = ir + (long)b * 36 * 64;
    for (int idx = tid; idx < 576; idx += 1024) {
      int row = idx >> 4, q4 = idx & 15;
      *(f32x4*)(Ys + row * 64 + q4 * 4) = *(const f32x4*)(Yg + row * 64 + q4 * 4);
    }
    __syncthreads();
    if (tid < 36) {
      float a = 0.f;
#pragma unroll
      for (int q4 = 0; q4 < 13; ++q4) {
        f32x4 v = *(const f32x4*)(Ys + tid * 64 + q4 * 4);
        a += v[0]*v[0] + v[1]*v[1] + v[2]*v[2] + v[3]*v[3];
      }
      ny[tid] = a;
    }
    __syncthreads();
    if (tid < 1008) {
      int ii = tid / 36, jj = tid - ii * 36;
      f32x4 yr[13];
#pragma unroll
      for (int q4 = 0; q4 < 13; ++q4) yr[q4] = *(const f32x4*)(Ys + jj * 64 + q4 * 4);
      float nyj = ny[jj];
      for (int i = ii; i < 36; i += 28) {
        float d = 0.f;
#pragma unroll
        for (int q4 = 0; q4 < 13; ++q4) {
          f32x4 xv = *(const f32x4*)(Ys + i * 64 + q4 * 4);
          d += xv[0]*yr[q4][0] + xv[1]*yr[q4][1] + xv[2]*yr[q4][2] + xv[3]*yr[q4][3];
        }
        Cs[i * 37 + jj] = (d - 0.5f * (ny[i] + nyj)) * INV_EPS_LN2;
      }
    }
    __syncthreads();
    int j = tid >> 2, kk = tid & 3;
    float Creg[9];
    if (j < 36) {
#pragma unroll
      for (int t = 0; t < 9; ++t) {
        int i2 = kk * 9 + t;
        Creg[t] = (i2 < 36) ? Cs[i2 * 37 + j] : 0.f;
      }
    }
    if (tid < 36) { sF[tid] = 0.f; sA[tid] = -LOG2_36; }
    __syncthreads();
    for (int h = 0; h < 40; ++h) {
      float m = -1e30f;
      if (j < 36) {
#pragma unroll
        for (int t = 0; t < 9; ++t) {
          int i2 = kk * 9 + t;
          if (i2 < 36) m = fmaxf(m, sA[i2] + Creg[t]);
        }
        m = fmaxf(m, __shfl_xor(m, 1)); m = fmaxf(m, __shfl_xor(m, 2));
      }
      __syncthreads();
      if (j < 36 && kk == 0) {
        ((h & 1) ? sF : sG)[j] = -EPS_LN2 * m;
        sA[j] = -LOG2_36 - m;
      }
      __syncthreads();
    }
    if (tid < 64) {
      float a = (tid < 36) ? sF[tid] + sG[tid] : 0.f;
#pragma unroll
      for (int o = 1; o < 64; o <<= 1) a += __shfl_xor(a, o);
      if (tid == 0) Syy[b] = a / 36.f;
    }
  }
}

// ---------------------------------------------------------------------------
// Final combine: w_dis -> w_pred, max with mix_pred, 2-way softmax.
// ---------------------------------------------------------------------------
__global__ void k_final(const float* __restrict__ mix, const float* __restrict__ sxy,
                        const float* __restrict__ sxx, const float* __restrict__ syy,
                        float* __restrict__ out) {
  int b = blockIdx.x * 64 + threadIdx.x;
  if (b < 128) {
    float w  = sxy[b] - 0.5f * (sxx[b] + syy[b]);
    float x0 = fmaxf(mix[b * 2 + 0], 1.0f - 0.01f * w);
    float x1 = fmaxf(mix[b * 2 + 1], 0.01f * w);
    float mx = fmaxf(x0, x1);
    float e0 = expf(x0 - mx), e1 = expf(x1 - mx);
    float inv = 1.f / (e0 + e1);
    out[b * 2 + 0] = e0 * inv;
    out[b * 2 + 1] = e1 * inv;
  }
}

// ---------------------------------------------------------------------------
extern "C" void kernel_launch(void* const* d_in, const int* in_sizes, int n_in,
                              void* d_out, int out_size, void* d_ws, size_t ws_size,
                              hipStream_t stream) {
  const float* txt_global = (const float*)d_in[0];
  const float* txt_region = (const float*)d_in[1];
  const float* img_global = (const float*)d_in[2];
  const float* img_region = (const float*)d_in[3];
  const float* social     = (const float*)d_in[4];
  const int*   attn_mask  = (const int*)  d_in[5];
  const float* W_stat = (const float*)d_in[6];  const float* b_stat = (const float*)d_in[7];
  const float* W_gt   = (const float*)d_in[8];  const float* b_gt   = (const float*)d_in[9];
  const float* W_gi   = (const float*)d_in[10]; const float* b_gi   = (const float*)d_in[11];
  const float* W_rt   = (const float*)d_in[12]; const float* b_rt   = (const float*)d_in[13];
  const float* W_ri   = (const float*)d_in[14]; const float* b_ri   = (const float*)d_in[15];
  const float* W_m1   = (const float*)d_in[16]; const float* b_m1   = (const float*)d_in[17];
  const float* W_m2   = (const float*)d_in[18]; const float* b_m2   = (const float*)d_in[19];

  float* ws = (float*)d_ws;
  float* ws_mix = ws;                    // 256
  float* ws_sxy = ws + 256;              // 128
  float* ws_sxx = ws + 384;              // 128
  float* ws_syy = ws + 512;              // 128
  short* ws_frt = (short*)(ws + 1024);   // 49152 shorts -> ends float 25600
  short* ws_fri = (short*)(ws + 25600);  // 131072 shorts -> ends float 91136
  float* ws_tr  = ws + 131072;           // [32768][64]
  float* ws_ir  = ws + 2228224;          // [4608][64]
  float* ws_cxx = ws + 2523136;          // [128][256][256]
  float* ws_pre = ws_cxx;                // [23][128][200]; consumed by k_pm
                                         // before k_sink overwrites with Cxx

  k_prep<<<456, 256, 0, stream>>>(W_rt, W_ri, ws_frt, ws_fri,
                                  txt_global, img_global, social,
                                  W_stat, b_stat, W_gt, W_gi, ws_pre);
  k_pm<<<712, 256, 0, stream>>>(txt_region, ws_frt, b_rt, ws_tr,
                                img_region, ws_fri, b_ri, ws_ir,
                                ws_pre, b_gt, b_gi,
                                W_m1, b_m1, W_m2, b_m2, ws_mix);
  k_sink<<<384, 1024, 0, stream>>>(ws_tr, ws_ir, attn_mask, ws_cxx,
                                   ws_sxy, ws_sxx, ws_syy);
  k_final<<<2, 64, 0, stream>>>(ws_mix, ws_sxy, ws_sxx, ws_syy, (float*)d_out);
}

// Round 6
// 341.879 us; speedup vs baseline: 1.0408x; 1.0408x over previous
//
#include <hip/hip_runtime.h>

typedef float  f32x4 __attribute__((ext_vector_type(4)));
typedef short  s16x8 __attribute__((ext_vector_type(8)));

#define EPS_LN2      0.0017328679513998632f   /* eps*ln2, eps = 0.0025 */
#define INV_EPS_LN2  577.0780163555852f       /* 1/(eps*ln2) */
#define LOG2_36      5.169925001442312f

__device__ __forceinline__ short f2bf(float x) {
  unsigned int u; __builtin_memcpy(&u, &x, 4);
  u = (u + 0x7FFFu + ((u >> 16) & 1u)) >> 16;   // RNE
  return (short)u;
}

// ---------------------------------------------------------------------------
// k_prep: blocks [0,88) pack W_rt/W_ri into MFMA B-frag order (bf16);
// blocks [88,456) K-split GEMM writing per-job slices pre[23][128][200].
// ---------------------------------------------------------------------------
__global__ __launch_bounds__(256) void k_prep(
    const float* __restrict__ W_rt, const float* __restrict__ W_ri,
    short* __restrict__ frt, short* __restrict__ fri,
    const float* __restrict__ txt, const float* __restrict__ img,
    const float* __restrict__ social,
    const float* __restrict__ W_stat, const float* __restrict__ b_stat,
    const float* __restrict__ W_gt, const float* __restrict__ W_gi,
    float* __restrict__ pre) {
  __shared__ float sA[32][128];
  int bid = blockIdx.x;
  if (bid < 88) {
    // ---- pack ----
    int slot = bid * 256 + threadIdx.x;   // 22528 total
    const float* W; short* dst; int f;
    if (slot < 6144) { W = W_rt; dst = frt; f = slot; }
    else             { W = W_ri; dst = fri; f = slot - 6144; }
    int k32 = f >> 8, rem = f & 255, ct = rem >> 6, l = rem & 63;
    int col = ct * 16 + (l & 15);
    int k0  = k32 * 32 + (l >> 4) * 8;
    s16x8 p;
#pragma unroll
    for (int c = 0; c < 8; ++c) {
      float v = (col < 50) ? W[(k0 + c) * 50 + col] : 0.f;
      p[c] = f2bf(v);
    }
    *(s16x8*)(dst + (long)f * 8) = p;
    return;
  }
  // ---- gemm: job slice pre[job] = A_chunk @ W_chunk ----
  int gb = bid - 88;
  int job = gb >> 4, rb = (gb >> 2) & 3, cb = gb & 3;
  int t = threadIdx.x, r0 = rb * 32;
  const float* W; int k0, klen;
  if (job < 6)       { k0 = job * 128;       klen = 128; W = W_gt; }
  else if (job == 6) { k0 = 0;               klen = 100; W = W_gt + 768 * 200; }
  else               { k0 = (job - 7) * 128; klen = 128; W = W_gi; }
  if (job == 6) {
    for (int idx = t; idx < 4096; idx += 256) {
      int r = idx >> 7, k = idx & 127;
      float v = 0.f;
      if (k < 100) {
        v = b_stat[k];
#pragma unroll
        for (int u = 0; u < 10; ++u) v += social[(r0 + r) * 10 + u] * W_stat[u * 100 + k];
        v = fmaxf(v, 0.f);
      }
      sA[r][k] = v;
    }
  } else {
    const float* A = (job < 6) ? txt : img;
    int K_A = (job < 6) ? 768 : 2048;
    for (int idx = t; idx < 4096; idx += 256) {
      int r = idx >> 7, k = idx & 127;
      sA[r][k] = A[(r0 + r) * K_A + k0 + k];
    }
  }
  __syncthreads();
  int c = cb * 64 + (t & 63), rg = t >> 6;
  if (c < 200) {
    float acc[8];
#pragma unroll
    for (int i = 0; i < 8; ++i) acc[i] = 0.f;
    for (int k4 = 0; k4 < klen; k4 += 4) {
      float w0 = W[(k0 + k4    ) * 200 + c];
      float w1 = W[(k0 + k4 + 1) * 200 + c];
      float w2 = W[(k0 + k4 + 2) * 200 + c];
      float w3 = W[(k0 + k4 + 3) * 200 + c];
#pragma unroll
      for (int i = 0; i < 8; ++i) {
        f32x4 a = *(const f32x4*)&sA[rg * 8 + i][k4];
        acc[i] += a[0]*w0 + a[1]*w1 + a[2]*w2 + a[3]*w3;
      }
    }
    float* dst = pre + (long)job * 25600;
#pragma unroll
    for (int i = 0; i < 8; ++i)
      dst[(r0 + rg * 8 + i) * 200 + c] = acc[i];
  }
}

// ---------------------------------------------------------------------------
// Projection GEMM body: register double-buffered A stream, STATIC buffers
// (bufA/bufB named separately; chunk loop fully unrolled so every index is a
// compile-time literal -- R5's buf[c&1] dynamic index demoted the buffers to
// scratch: VGPR=60, WRITE_SIZE 9->24 MB, 105us). Chunks of 4 k32 (128 cols).
// out[M][64] = relu(A[M][K] @ W + bias). One block = 64 rows (4 waves x 16).
// ---------------------------------------------------------------------------
template<int K32>
__device__ __forceinline__ void proj_body(const float* __restrict__ A,
                                          const short* __restrict__ Bf,
                                          const float* __restrict__ bias,
                                          float* __restrict__ out, int bid) {
  constexpr int NC = K32 / 4;                   // 6 (txt) or 16 (img), even
  int wave = threadIdx.x >> 6, lane = threadIdx.x & 63;
  int rl = lane & 15, q = lane >> 4;
  int row0 = bid * 64 + wave * 16;
  const int K = K32 * 32;
  const float* ar = A + (long)(row0 + rl) * K + q * 8;
  const short* bfl = Bf + lane * 8;

  f32x4 bufA[8], bufB[8];
#pragma unroll
  for (int u = 0; u < 8; ++u)
    bufA[u] = *(const f32x4*)(ar + (u >> 1) * 32 + (u & 1) * 4);
#pragma unroll
  for (int u = 0; u < 8; ++u)
    bufB[u] = *(const f32x4*)(ar + 128 + (u >> 1) * 32 + (u & 1) * 4);

  f32x4 acc[4];
#pragma unroll
  for (int ct = 0; ct < 4; ++ct) acc[ct] = (f32x4){0.f, 0.f, 0.f, 0.f};

#pragma unroll
  for (int c = 0; c < NC; c += 2) {
    // ---- compute chunk c from bufA ----
#pragma unroll
    for (int kk = 0; kk < 4; ++kk) {
      f32x4 a0 = bufA[kk * 2], a1 = bufA[kk * 2 + 1];
      s16x8 af;
      af[0]=f2bf(a0[0]); af[1]=f2bf(a0[1]); af[2]=f2bf(a0[2]); af[3]=f2bf(a0[3]);
      af[4]=f2bf(a1[0]); af[5]=f2bf(a1[1]); af[6]=f2bf(a1[2]); af[7]=f2bf(a1[3]);
      const short* bp = bfl + (long)(c * 4 + kk) * 2048;
#pragma unroll
      for (int ct = 0; ct < 4; ++ct) {
        s16x8 bfr = *(const s16x8*)(bp + ct * 512);
        acc[ct] = __builtin_amdgcn_mfma_f32_16x16x32_bf16(af, bfr, acc[ct], 0, 0, 0);
      }
    }
    if (c + 2 < NC) {                           // refill bufA with chunk c+2
      const float* src = ar + (c + 2) * 128;
#pragma unroll
      for (int u = 0; u < 8; ++u)
        bufA[u] = *(const f32x4*)(src + (u >> 1) * 32 + (u & 1) * 4);
    }
    // ---- compute chunk c+1 from bufB ----
#pragma unroll
    for (int kk = 0; kk < 4; ++kk) {
      f32x4 a0 = bufB[kk * 2], a1 = bufB[kk * 2 + 1];
      s16x8 af;
      af[0]=f2bf(a0[0]); af[1]=f2bf(a0[1]); af[2]=f2bf(a0[2]); af[3]=f2bf(a0[3]);
      af[4]=f2bf(a1[0]); af[5]=f2bf(a1[1]); af[6]=f2bf(a1[2]); af[7]=f2bf(a1[3]);
      const short* bp = bfl + (long)((c + 1) * 4 + kk) * 2048;
#pragma unroll
      for (int ct = 0; ct < 4; ++ct) {
        s16x8 bfr = *(const s16x8*)(bp + ct * 512);
        acc[ct] = __builtin_amdgcn_mfma_f32_16x16x32_bf16(af, bfr, acc[ct], 0, 0, 0);
      }
    }
    if (c + 3 < NC) {                           // refill bufB with chunk c+3
      const float* src = ar + (c + 3) * 128;
#pragma unroll
      for (int u = 0; u < 8; ++u)
        bufB[u] = *(const f32x4*)(src + (u >> 1) * 32 + (u & 1) * 4);
    }
  }
#pragma unroll
  for (int ct = 0; ct < 4; ++ct) {
    int col = ct * 16 + rl;
    float bv = (col < 50) ? bias[col] : 0.f;
#pragma unroll
    for (int r = 0; r < 4; ++r) {
      int grow = row0 + q * 4 + r;               // D row = quad*4+reg (m89)
      float o = fmaxf(acc[ct][r] + bv, 0.f);
      out[(long)grow * 64 + col] = (col < 50) ? o : 0.f;
    }
  }
}

// MLP tail body: one block per batch row; sums the 23 per-job GEMM slices.
__device__ __forceinline__ void mix_body(
    int r, const float* __restrict__ pre,
    const float* __restrict__ b_gt, const float* __restrict__ b_gi,
    const float* __restrict__ W_m1, const float* __restrict__ b_m1,
    const float* __restrict__ W_m2, const float* __restrict__ b_m2,
    float* __restrict__ mix, char* smem) {
  float* sm = (float*)smem;          // [200]
  float* sh = (float*)(smem + 800);  // [100]
  int t = threadIdx.x;
  if (t < 200) {
    float s1 = b_gt[t], s2 = b_gi[t];
#pragma unroll
    for (int j = 0; j < 7; ++j)  s1 += pre[(long)j * 25600 + r * 200 + t];
#pragma unroll
    for (int j = 7; j < 23; ++j) s2 += pre[(long)j * 25600 + r * 200 + t];
    sm[t] = fmaxf(s1, 0.f) + fmaxf(s2, 0.f);
  }
  __syncthreads();
  if (t < 100) {
    float a = b_m1[t];
#pragma unroll 4
    for (int k = 0; k < 200; ++k) a += sm[k] * W_m1[k * 100 + t];
    sh[t] = fmaxf(a, 0.f);
  }
  __syncthreads();
  if (t < 2) {
    float a = b_m2[t];
    for (int k = 0; k < 100; ++k) a += sh[k] * W_m2[k * 2 + t];
    mix[r * 2 + t] = a;
  }
}

// Merged: blocks [0,128) mix rows, [128,640) txt proj, [640,712) img proj.
__global__ __launch_bounds__(256)
__attribute__((amdgpu_waves_per_eu(4, 4)))
void k_pm(
    const float* __restrict__ txt_region, const short* __restrict__ frt,
    const float* __restrict__ b_rt, float* __restrict__ tr,
    const float* __restrict__ img_region, const short* __restrict__ fri,
    const float* __restrict__ b_ri, float* __restrict__ ir,
    const float* __restrict__ pre,
    const float* __restrict__ b_gt, const float* __restrict__ b_gi,
    const float* __restrict__ W_m1, const float* __restrict__ b_m1,
    const float* __restrict__ W_m2, const float* __restrict__ b_m2,
    float* __restrict__ mix) {
  __shared__ __align__(16) char smem[2048];
  int bid = blockIdx.x;
  if (bid < 128)      mix_body(bid, pre, b_gt, b_gi, W_m1, b_m1, W_m2, b_m2, mix, smem);
  else if (bid < 640) proj_body<24>(txt_region, frt, b_rt, tr, bid - 128);
  else                proj_body<64>(img_region, fri, b_ri, ir, bid - 640);
}

// ---------------------------------------------------------------------------
// Merged Sinkhorn kernel, MAX-PLUS. role 0: xx (n x n), role 1: xy (n x 36),
// role 2: yy (36 x 36). waves_per_eu(4,4): 128-VGPR budget, Creg in regs.
// ---------------------------------------------------------------------------
#define SK_SMEM 50736

__global__ __launch_bounds__(1024)
__attribute__((amdgpu_waves_per_eu(4, 4)))
void k_sink(
    const float* __restrict__ tr, const float* __restrict__ ir,
    const int* __restrict__ amask, float* __restrict__ Cxx,
    float* __restrict__ Sxy, float* __restrict__ Sxx, float* __restrict__ Syy) {
  __shared__ __align__(16) char smem[SK_SMEM];
  int role = blockIdx.x >> 7;
  int b    = blockIdx.x & 127;
  int tid  = threadIdx.x;

  if (role == 0) {
    // ====================== XX ======================
    short* Xf    = (short*)smem;                 // 32 KB
    float* norms = (float*)(smem + 32768);       // [256]
    float* sA    = (float*)(smem + 33792);       // [256]
    float* sF    = (float*)(smem + 34816);       // [256]
    float* sG    = (float*)(smem + 35840);       // [256]
    float* sPm   = (float*)(smem + 36864);       // [4][256]
    int*   nsh   = (int*)  (smem + 40960);
    if (tid < 64) {
      int c = 0;
      for (int i = tid; i < 256; i += 64) c += amask[b * 256 + i];
#pragma unroll
      for (int o = 1; o < 64; o <<= 1) c += __shfl_xor(c, o);
      if (tid == 0) *nsh = c;
    }
    const float* Xg = tr + (long)b * 256 * 64;
    for (int slot = tid; slot < 2048; slot += 1024) {
      int t = slot >> 7, k32 = (slot >> 6) & 1, l = slot & 63;
      int row = t * 16 + (l & 15), k0 = k32 * 32 + (l >> 4) * 8;
      const float* src = Xg + row * 64 + k0;
      f32x4 a0 = *(const f32x4*)src, a1 = *(const f32x4*)(src + 4);
      s16x8 p;
      p[0]=f2bf(a0[0]); p[1]=f2bf(a0[1]); p[2]=f2bf(a0[2]); p[3]=f2bf(a0[3]);
      p[4]=f2bf(a1[0]); p[5]=f2bf(a1[1]); p[6]=f2bf(a1[2]); p[7]=f2bf(a1[3]);
      *(s16x8*)(Xf + slot * 8) = p;
    }
    __syncthreads();
    int n = *nsh;
    // G = X X^T via MFMA. wave wv owns 16-row strip.
    int wv = tid >> 6, lane = tid & 63, q = lane >> 4;
    f32x4 acc[16];
#pragma unroll
    for (int ct = 0; ct < 16; ++ct) acc[ct] = (f32x4){0.f, 0.f, 0.f, 0.f};
    s16x8 afr0 = *(const s16x8*)(Xf + ((wv * 2 + 0) * 64 + lane) * 8);
    s16x8 afr1 = *(const s16x8*)(Xf + ((wv * 2 + 1) * 64 + lane) * 8);
#pragma unroll
    for (int ct = 0; ct < 16; ++ct) {
      s16x8 b0 = *(const s16x8*)(Xf + ((ct * 2 + 0) * 64 + lane) * 8);
      s16x8 b1 = *(const s16x8*)(Xf + ((ct * 2 + 1) * 64 + lane) * 8);
      acc[ct] = __builtin_amdgcn_mfma_f32_16x16x32_bf16(afr0, b0, acc[ct], 0, 0, 0);
      acc[ct] = __builtin_amdgcn_mfma_f32_16x16x32_bf16(afr1, b1, acc[ct], 0, 0, 0);
    }
#pragma unroll
    for (int r = 0; r < 4; ++r) {                 // diag of tile (wv,wv) = ||x||^2
      int m_ = q * 4 + r;
      if ((lane & 15) == m_) norms[wv * 16 + m_] = acc[wv][r];
    }
    __syncthreads();
    float* Cwb = Cxx + (long)b * 65536;           // D = -C/(eps ln2), f32, global
    if (wv * 16 < n) {                            // skip row-tiles entirely >= n
#pragma unroll
      for (int ct = 0; ct < 16; ++ct) {
        int gj = ct * 16 + (lane & 15);
        float nj = norms[gj];
#pragma unroll
        for (int r = 0; r < 4; ++r) {
          int gi = wv * 16 + q * 4 + r;
          Cwb[gi * 256 + gj] = (acc[ct][r] - 0.5f * (norms[gi] + nj)) * INV_EPS_LN2;
        }
      }
    }
    __syncthreads();
    // kk wave-uniform so prefix-skipping has no divergence
    int kk = tid >> 8, j = tid & 255, i0 = kk * 64;
    int iend = n - i0; if (iend > 64) iend = 64;
    float Creg[64];
    if (j < n) {
#pragma unroll
      for (int ch = 0; ch < 4; ++ch) {
        if (ch * 16 < iend) {
#pragma unroll
          for (int u = 0; u < 16; ++u)
            Creg[ch * 16 + u] = Cwb[(i0 + ch * 16 + u) * 256 + j];
        }
      }
    }
    float log2n = log2f((float)n);
    if (tid < 256) { sF[tid] = 0.f; sA[tid] = (tid < n) ? -log2n : -1e30f; }
    __syncthreads();
    const float* ap = sA + i0;
    for (int h = 0; h < 40; ++h) {
      float m = -1e30f;
      if (j < n) {
#pragma unroll
        for (int ch = 0; ch < 4; ++ch) {
          if (ch * 16 < iend) {                   // wave-uniform chunk skip
            const float* app = ap + ch * 16;
            f32x4 A0 = *(const f32x4*)(app);
            f32x4 A1 = *(const f32x4*)(app + 4);
            f32x4 A2 = *(const f32x4*)(app + 8);
            f32x4 A3 = *(const f32x4*)(app + 12);
            float x0 = A0[0]+Creg[ch*16+0],  x1 = A0[1]+Creg[ch*16+1];
            float x2 = A0[2]+Creg[ch*16+2],  x3 = A0[3]+Creg[ch*16+3];
            float x4 = A1[0]+Creg[ch*16+4],  x5 = A1[1]+Creg[ch*16+5];
            float x6 = A1[2]+Creg[ch*16+6],  x7 = A1[3]+Creg[ch*16+7];
            float x8 = A2[0]+Creg[ch*16+8],  x9 = A2[1]+Creg[ch*16+9];
            float xa = A2[2]+Creg[ch*16+10], xb = A2[3]+Creg[ch*16+11];
            float xc = A3[0]+Creg[ch*16+12], xd = A3[1]+Creg[ch*16+13];
            float xe = A3[2]+Creg[ch*16+14], xf = A3[3]+Creg[ch*16+15];
            // max3 trees (v_max3_f32)
            float y0 = fmaxf(fmaxf(x0, x1), x2);
            float y1 = fmaxf(fmaxf(x3, x4), x5);
            float y2 = fmaxf(fmaxf(x6, x7), x8);
            float y3 = fmaxf(fmaxf(x9, xa), xb);
            float y4 = fmaxf(fmaxf(xc, xd), xe);
            float z0 = fmaxf(fmaxf(y0, y1), y2);
            float z1 = fmaxf(fmaxf(y3, y4), xf);
            m = fmaxf(fmaxf(m, z0), z1);
          }
        }
      }
      sPm[kk * 256 + j] = m;
      __syncthreads();
      if (tid < 256) {
        float m4 = fmaxf(fmaxf(sPm[tid], sPm[256 + tid]),
                         fmaxf(sPm[512 + tid], sPm[768 + tid]));
        if (tid < n) {
          ((h & 1) ? sF : sG)[tid] = -EPS_LN2 * m4;
          sA[tid] = -log2n - m4;
        }
      }
      __syncthreads();
    }
    if (tid < 64) {
      float a = 0.f;
      for (int i = tid; i < n; i += 64) a += sF[i] + sG[i];
#pragma unroll
      for (int o = 1; o < 64; o <<= 1) a += __shfl_xor(a, o);
      if (tid == 0) Sxx[b] = a / n;
    }
  } else if (role == 1) {
    // ====================== XY ======================
    float* Ys  = (float*)smem;                    // [36][64]
    float* Cs  = (float*)(smem + 9216);           // [256][37]
    float* nx  = (float*)(smem + 47104);          // [256]
    float* ny  = (float*)(smem + 48128);          // [36]
    float* sA  = (float*)(smem + 48288);          // padded alpha [272]
    float* sB  = (float*)(smem + 49376);          // beta [36]
    float* sF  = (float*)(smem + 49536);          // [256]
    float* sG  = (float*)(smem + 50560);          // [36]
    int*   nsh = (int*)  (smem + 50720);
    if (tid < 64) {
      int c = 0;
      for (int i = tid; i < 256; i += 64) c += amask[b * 256 + i];
#pragma unroll
      for (int o = 1; o < 64; o <<= 1) c += __shfl_xor(c, o);
      if (tid == 0) *nsh = c;
    }
    const float* Xg = tr + (long)b * 256 * 64;
    const float* Yg = ir + (long)b * 36 * 64;
    for (int idx = tid; idx < 576; idx += 1024) {
      int row = idx >> 4, q4 = idx & 15;
      *(f32x4*)(Ys + row * 64 + q4 * 4) = *(const f32x4*)(Yg + row * 64 + q4 * 4);
    }
    __syncthreads();
    int n = *nsh;
    if (tid < 256) {
      float a = 0.f;
#pragma unroll
      for (int q4 = 0; q4 < 13; ++q4) {
        f32x4 v = *(const f32x4*)(Xg + tid * 64 + q4 * 4);
        a += v[0]*v[0] + v[1]*v[1] + v[2]*v[2] + v[3]*v[3];
      }
      nx[tid] = a;
    } else if (tid < 292) {
      int jj = tid - 256; float a = 0.f;
#pragma unroll
      for (int q4 = 0; q4 < 13; ++q4) {
        f32x4 v = *(const f32x4*)(Ys + jj * 64 + q4 * 4);
        a += v[0]*v[0] + v[1]*v[1] + v[2]*v[2] + v[3]*v[3];
      }
      ny[jj] = a;
    }
    __syncthreads();
    if (tid < 1008) {
      int ii = tid / 36, jj = tid - ii * 36;
      f32x4 yr[13];
#pragma unroll
      for (int q4 = 0; q4 < 13; ++q4) yr[q4] = *(const f32x4*)(Ys + jj * 64 + q4 * 4);
      float nyj = ny[jj];
      for (int i = ii; i < 256; i += 28) {
        float d = 0.f;
#pragma unroll
        for (int q4 = 0; q4 < 13; ++q4) {
          f32x4 xv = *(const f32x4*)(Xg + i * 64 + q4 * 4);
          d += xv[0]*yr[q4][0] + xv[1]*yr[q4][1] + xv[2]*yr[q4][2] + xv[3]*yr[q4][3];
        }
        Cs[i * 37 + jj] = (d - 0.5f * (nx[i] + nyj)) * INV_EPS_LN2;
      }
    }
    __syncthreads();
    int jg = tid >> 4, kg = tid & 15;             // g-role: column jg, slice kg
    float Cg[16];
    if (jg < 36) {
#pragma unroll
      for (int t = 0; t < 16; ++t) Cg[t] = Cs[(kg * 16 + t) * 37 + jg];
    }
    int fi = tid >> 2, kf = tid & 3;              // f-role: row fi, slice kf
    float Cf[9];
#pragma unroll
    for (int t = 0; t < 9; ++t) {
      int jj2 = kf * 9 + t;
      Cf[t] = (jj2 < 36) ? Cs[fi * 37 + jj2] : 0.f;
    }
    float log2n = log2f((float)n);
    if (tid < 256) { sF[tid] = 0.f; sA[tid + (tid >> 4)] = -log2n; }
    __syncthreads();
    const float* agp = sA + kg * 17;
    int gend = n - kg * 16; if (gend > 16) gend = 16;
    for (int it = 0; it < 20; ++it) {
      float gm = -1e30f;
      if (jg < 36) {
#pragma unroll
        for (int t = 0; t < 16; ++t)
          if (t < gend) gm = fmaxf(gm, agp[t] + Cg[t]);
        gm = fmaxf(gm, __shfl_xor(gm, 1)); gm = fmaxf(gm, __shfl_xor(gm, 2));
        gm = fmaxf(gm, __shfl_xor(gm, 4)); gm = fmaxf(gm, __shfl_xor(gm, 8));
      }
      __syncthreads();
      if (jg < 36 && kg == 0) {
        sG[jg] = -EPS_LN2 * gm;
        sB[jg] = -LOG2_36 - gm;
      }
      __syncthreads();
      float fm = -1e30f;
#pragma unroll
      for (int t = 0; t < 9; ++t) {
        int jj2 = kf * 9 + t;
        if (jj2 < 36) fm = fmaxf(fm, sB[jj2] + Cf[t]);
      }
      fm = fmaxf(fm, __shfl_xor(fm, 1)); fm = fmaxf(fm, __shfl_xor(fm, 2));
      __syncthreads();
      if (kf == 0 && fi < n) {
        sF[fi] = -EPS_LN2 * fm;
        sA[fi + (fi >> 4)] = -log2n - fm;
      }
      __syncthreads();
    }
    if (tid < 64) {
      float a = 0.f;
      for (int i = tid; i < n; i += 64) a += sF[i];
      float g = (tid < 36) ? sG[tid] : 0.f;
#pragma unroll
      for (int o = 1; o < 64; o <<= 1) { a += __shfl_xor(a, o); g += __shfl_xor(g, o); }
      if (tid == 0) Sxy[b] = a / n + g / 36.f;
    }
  } else {
    // ====================== YY ======================
    float* Ys = (float*)smem;                     // [36][64]
    float* Cs = (float*)(smem + 9216);            // [36][37]
    float* ny = (float*)(smem + 48128);
    float* sA = (float*)(smem + 48288);           // [36]
    float* sF = (float*)(smem + 49536);
    float* sG = (float*)(smem + 50560);
    const float* Yg = ir + (long)b * 36 * 64;
    for (int idx = tid; idx < 576; idx += 1024) {
      int row = idx >> 4, q4 = idx & 15;
      *(f32x4*)(Ys + row * 64 + q4 * 4) = *(const f32x4*)(Yg + row * 64 + q4 * 4);
    }
    __syncthreads();
    if (tid < 36) {
      float a = 0.f;
#pragma unroll
      for (int q4 = 0; q4 < 13; ++q4) {
        f32x4 v = *(const f32x4*)(Ys + tid * 64 + q4 * 4);
        a += v[0]*v[0] + v[1]*v[1] + v[2]*v[2] + v[3]*v[3];
      }
      ny[tid] = a;
    }
    __syncthreads();
    if (tid < 1008) {
      int ii = tid / 36, jj = tid - ii * 36;
      f32x4 yr[13];
#pragma unroll
      for (int q4 = 0; q4 < 13; ++q4) yr[q4] = *(const f32x4*)(Ys + jj * 64 + q4 * 4);
      float nyj = ny[jj];
      for (int i = ii; i < 36; i += 28) {
        float d = 0.f;
#pragma unroll
        for (int q4 = 0; q4 < 13; ++q4) {
          f32x4 xv = *(const f32x4*)(Ys + i * 64 + q4 * 4);
          d += xv[0]*yr[q4][0] + xv[1]*yr[q4][1] + xv[2]*yr[q4][2] + xv[3]*yr[q4][3];
        }
        Cs[i * 37 + jj] = (d - 0.5f * (ny[i] + nyj)) * INV_EPS_LN2;
      }
    }
    __syncthreads();
    int j = tid >> 2, kk = tid & 3;
    float Creg[9];
    if (j < 36) {
#pragma unroll
      for (int t = 0; t < 9; ++t) {
        int i2 = kk * 9 + t;
        Creg[t] = (i2 < 36) ? Cs[i2 * 37 + j] : 0.f;
      }
    }
    if (tid < 36) { sF[tid] = 0.f; sA[tid] = -LOG2_36; }
    __syncthreads();
    for (int h = 0; h < 40; ++h) {
      float m = -1e30f;
      if (j < 36) {
#pragma unroll
        for (int t = 0; t < 9; ++t) {
          int i2 = kk * 9 + t;
          if (i2 < 36) m = fmaxf(m, sA[i2] + Creg[t]);
        }
        m = fmaxf(m, __shfl_xor(m, 1)); m = fmaxf(m, __shfl_xor(m, 2));
      }
      __syncthreads();
      if (j < 36 && kk == 0) {
        ((h & 1) ? sF : sG)[j] = -EPS_LN2 * m;
        sA[j] = -LOG2_36 - m;
      }
      __syncthreads();
    }
    if (tid < 64) {
      float a = (tid < 36) ? sF[tid] + sG[tid] : 0.f;
#pragma unroll
      for (int o = 1; o < 64; o <<= 1) a += __shfl_xor(a, o);
      if (tid == 0) Syy[b] = a / 36.f;
    }
  }
}

// ---------------------------------------------------------------------------
// Final combine: w_dis -> w_pred, max with mix_pred, 2-way softmax.
// ---------------------------------------------------------------------------
__global__ void k_final(const float* __restrict__ mix, const float* __restrict__ sxy,
                        const float* __restrict__ sxx, const float* __restrict__ syy,
                        float* __restrict__ out) {
  int b = blockIdx.x * 64 + threadIdx.x;
  if (b < 128) {
    float w  = sxy[b] - 0.5f * (sxx[b] + syy[b]);
    float x0 = fmaxf(mix[b * 2 + 0], 1.0f - 0.01f * w);
    float x1 = fmaxf(mix[b * 2 + 1], 0.01f * w);
    float mx = fmaxf(x0, x1);
    float e0 = expf(x0 - mx), e1 = expf(x1 - mx);
    float inv = 1.f / (e0 + e1);
    out[b * 2 + 0] = e0 * inv;
    out[b * 2 + 1] = e1 * inv;
  }
}

// ---------------------------------------------------------------------------
extern "C" void kernel_launch(void* const* d_in, const int* in_sizes, int n_in,
                              void* d_out, int out_size, void* d_ws, size_t ws_size,
                              hipStream_t stream) {
  const float* txt_global = (const float*)d_in[0];
  const float* txt_region = (const float*)d_in[1];
  const float* img_global = (const float*)d_in[2];
  const float* img_region = (const float*)d_in[3];
  const float* social     = (const float*)d_in[4];
  const int*   attn_mask  = (const int*)  d_in[5];
  const float* W_stat = (const float*)d_in[6];  const float* b_stat = (const float*)d_in[7];
  const float* W_gt   = (const float*)d_in[8];  const float* b_gt   = (const float*)d_in[9];
  const float* W_gi   = (const float*)d_in[10]; const float* b_gi   = (const float*)d_in[11];
  const float* W_rt   = (const float*)d_in[12]; const float* b_rt   = (const float*)d_in[13];
  const float* W_ri   = (const float*)d_in[14]; const float* b_ri   = (const float*)d_in[15];
  const float* W_m1   = (const float*)d_in[16]; const float* b_m1   = (const float*)d_in[17];
  const float* W_m2   = (const float*)d_in[18]; const float* b_m2   = (const float*)d_in[19];

  float* ws = (float*)d_ws;
  float* ws_mix = ws;                    // 256
  float* ws_sxy = ws + 256;              // 128
  float* ws_sxx = ws + 384;              // 128
  float* ws_syy = ws + 512;              // 128
  short* ws_frt = (short*)(ws + 1024);   // 49152 shorts -> ends float 25600
  short* ws_fri = (short*)(ws + 25600);  // 131072 shorts -> ends float 91136
  float* ws_tr  = ws + 131072;           // [32768][64]
  float* ws_ir  = ws + 2228224;          // [4608][64]
  float* ws_cxx = ws + 2523136;          // [128][256][256]
  float* ws_pre = ws_cxx;                // [23][128][200]; consumed by k_pm
                                         // before k_sink overwrites with Cxx

  k_prep<<<456, 256, 0, stream>>>(W_rt, W_ri, ws_frt, ws_fri,
                                  txt_global, img_global, social,
                                  W_stat, b_stat, W_gt, W_gi, ws_pre);
  k_pm<<<712, 256, 0, stream>>>(txt_region, ws_frt, b_rt, ws_tr,
                                img_region, ws_fri, b_ri, ws_ir,
                                ws_pre, b_gt, b_gi,
                                W_m1, b_m1, W_m2, b_m2, ws_mix);
  k_sink<<<384, 1024, 0, stream>>>(ws_tr, ws_ir, attn_mask, ws_cxx,
                                   ws_sxy, ws_sxx, ws_syy);
  k_final<<<2, 64, 0, stream>>>(ws_mix, ws_sxy, ws_sxx, ws_syy, (float*)d_out);
}